// Round 4
// baseline (466.925 us; speedup 1.0000x reference)
//
#include <hip/hip_runtime.h>

constexpr int IN_FEAT = 256;
constexpr int HID     = 64;
constexpr int OUT     = 32;

typedef _Float16 half8 __attribute__((ext_vector_type(8)));
typedef float    f32x4 __attribute__((ext_vector_type(4)));

// ---------------------------------------------------------------------------
// Fold the two linears into W = fc1_w^T @ gcn_w  [256,32], bhw = fc1_b @ gcn_w.
// Emit W as f16, TRANSPOSED [c][k] and XOR-swizzled for conflict-free b128
// LDS reads in the MFMA gemm:  f16 offset = c*256 + ((k>>3)^(c&7))*8 + (k&7).
// ---------------------------------------------------------------------------
__global__ __launch_bounds__(256) void prep_W(
    const float* __restrict__ fc1_w,   // [HID][IN_FEAT]
    const float* __restrict__ fc1_b,   // [HID]
    const float* __restrict__ gcn_w,   // [HID][OUT]
    _Float16* __restrict__ wsw,        // [32*256] f16, swizzled image
    float* __restrict__ bhw)           // [OUT]
{
    int idx = blockIdx.x * 256 + threadIdx.x;   // 0 .. 8191
    int k = idx >> 5;
    int c = idx & 31;
    float acc = 0.f;
#pragma unroll
    for (int h = 0; h < HID; ++h)
        acc += fc1_w[h * IN_FEAT + k] * gcn_w[h * OUT + c];
    wsw[c * 256 + (((k >> 3) ^ (c & 7)) << 3) + (k & 7)] = (_Float16)acc;

    if (idx < OUT) {
        float b = 0.f;
#pragma unroll
        for (int h = 0; h < HID; ++h)
            b += fc1_b[h] * gcn_w[h * OUT + idx];
        bhw[idx] = b;
    }
}

// ---------------------------------------------------------------------------
// Degree counting + CSR offsets (counting sort, cursor folded into off).
// ---------------------------------------------------------------------------
__global__ __launch_bounds__(256) void zero_cnt(int* __restrict__ cnt, int n)
{
    int i = blockIdx.x * 256 + threadIdx.x;
    if (i < n) cnt[i] = 0;
}

__global__ __launch_bounds__(256) void count_deg(
    const int* __restrict__ dst, int* __restrict__ cnt, int E)
{
    int e = blockIdx.x * 256 + threadIdx.x;
    if (e < E) atomicAdd(&cnt[dst[e]], 1);
}

__global__ __launch_bounds__(256) void scan1(
    const int* __restrict__ cnt, int* __restrict__ bsum, int n)
{
    int t = threadIdx.x;
    int i = blockIdx.x * 1024 + t * 4;
    int s = 0;
    if (i + 3 < n) {
        int4 v = *reinterpret_cast<const int4*>(&cnt[i]);
        s = v.x + v.y + v.z + v.w;
    } else {
        for (int j = 0; j < 4; ++j) if (i + j < n) s += cnt[i + j];
    }
    for (int d = 32; d; d >>= 1) s += __shfl_down(s, d, 64);
    __shared__ int ws[4];
    if ((t & 63) == 0) ws[t >> 6] = s;
    __syncthreads();
    if (t == 0) bsum[blockIdx.x] = ws[0] + ws[1] + ws[2] + ws[3];
}

__global__ void scan2(int* __restrict__ bsum, int nb)
{
    if (threadIdx.x == 0 && blockIdx.x == 0) {
        int acc = 0;
        for (int i = 0; i < nb; ++i) { int v = bsum[i]; bsum[i] = acc; acc += v; }
    }
}

__global__ __launch_bounds__(256) void scan3(
    const int* __restrict__ cnt, const int* __restrict__ bsum,
    int* __restrict__ off, float* __restrict__ dinv, int n)
{
    int t = threadIdx.x;
    int i = blockIdx.x * 1024 + t * 4;
    int c0 = 0, c1 = 0, c2 = 0, c3 = 0;
    if (i + 3 < n) {
        int4 v = *reinterpret_cast<const int4*>(&cnt[i]);
        c0 = v.x; c1 = v.y; c2 = v.z; c3 = v.w;
    } else {
        if (i     < n) c0 = cnt[i];
        if (i + 1 < n) c1 = cnt[i + 1];
        if (i + 2 < n) c2 = cnt[i + 2];
        if (i + 3 < n) c3 = cnt[i + 3];
    }
    int s = c0 + c1 + c2 + c3;
    int lane = t & 63;
    int incl = s;
    for (int d = 1; d < 64; d <<= 1) {
        int u = __shfl_up(incl, d, 64);
        if (lane >= d) incl += u;
    }
    __shared__ int wtot[4];
    if (lane == 63) wtot[t >> 6] = incl;
    __syncthreads();
    int w = t >> 6;
    int wbase = 0;
    for (int j = 0; j < 4; ++j) if (j < w) wbase += wtot[j];
    int ebase = bsum[blockIdx.x] + wbase + (incl - s);

    if (i     < n) { off[i]   = ebase;            dinv[i]   = rsqrtf((float)(c0 + 1)); }
    if (i + 1 < n) { off[i+1] = ebase + c0;       dinv[i+1] = rsqrtf((float)(c1 + 1)); }
    if (i + 2 < n) { off[i+2] = ebase + c0 + c1;  dinv[i+2] = rsqrtf((float)(c2 + 1)); }
    if (i + 3 < n) { off[i+3] = ebase + c0+c1+c2; dinv[i+3] = rsqrtf((float)(c3 + 1)); }
}

// permute edges into dst-grouped src list; off becomes the END pointer.
__global__ __launch_bounds__(256) void permute_edges(
    const int* __restrict__ src, const int* __restrict__ dst,
    int* __restrict__ off, int* __restrict__ edata, int E)
{
    int e = blockIdx.x * 256 + threadIdx.x;
    if (e >= E) return;
    int s = src[e];
    int d = dst[e];
    int pos = atomicAdd(&off[d], 1);
    edata[pos] = s;
}

// ---------------------------------------------------------------------------
// MFMA GEMM: hw = f16(x) @ f16(W) + bhw.
// Block: 256 thr / 4 waves, 64 rows. LDS: xs [64][256] f16 + wt [32][256] f16
// (both XOR-swizzled per 16B slot: slot = chunk ^ (row&7)) = 48 KB -> 3 blk/CU.
// Wave w: rows w*16..+15, cols 0..31 via 2x mfma_f32_16x16x32_f16 per k-step.
// Fragment maps (CDNA contiguous-8):
//   A[r][k]: lane=r+16*(k/8), elem=k%8;  B[k][c]: lane=c+16*(k/8), elem=k%8;
//   D[r][c]: lane=c+16*(r/4), reg=r%4.
// ---------------------------------------------------------------------------
__global__ __launch_bounds__(256) void gemm_mfma(
    const float* __restrict__ x,        // [N][256] f32
    const _Float16* __restrict__ wsw,   // [32*256] f16 swizzled
    const float* __restrict__ bhw,      // [32]
    float* __restrict__ hw,             // [N][32]
    int n)
{
    __shared__ __align__(16) _Float16 xs[64 * 256];   // 32 KB
    __shared__ __align__(16) _Float16 wt[32 * 256];   // 16 KB

    int t = threadIdx.x;

    // stage W: straight 16 KB copy (already swizzled in global)
    {
        const float4* wg = reinterpret_cast<const float4*>(wsw);
        float4* wl = reinterpret_cast<float4*>(wt);
#pragma unroll
        for (int i = 0; i < 4; ++i)
            wl[t + 256 * i] = wg[t + 256 * i];
    }

    // stage x: 64 rows. half-wave h handles rows h, h+8, ..., lanes cover k.
    int row0 = blockIdx.x * 64;
    {
        int hwid = t >> 5;          // 0..7
        int lk   = t & 31;          // k-chunk (8 floats each)
        const float4* xg = reinterpret_cast<const float4*>(x);
        float4 A[8], B[8];
#pragma unroll
        for (int g = 0; g < 8; ++g) {
            int r = g * 8 + hwid;
            int row = row0 + r;
            A[g] = make_float4(0.f, 0.f, 0.f, 0.f);
            B[g] = make_float4(0.f, 0.f, 0.f, 0.f);
            if (row < n) {
                const float4* p = xg + (size_t)row * 64 + lk * 2;
                A[g] = p[0];
                B[g] = p[1];
            }
        }
        char* xsb = reinterpret_cast<char*>(xs);
#pragma unroll
        for (int g = 0; g < 8; ++g) {
            int r = g * 8 + hwid;
            half8 h;
            h[0] = (_Float16)A[g].x; h[1] = (_Float16)A[g].y;
            h[2] = (_Float16)A[g].z; h[3] = (_Float16)A[g].w;
            h[4] = (_Float16)B[g].x; h[5] = (_Float16)B[g].y;
            h[6] = (_Float16)B[g].z; h[7] = (_Float16)B[g].w;
            int slot = lk ^ (r & 7);
            *reinterpret_cast<half8*>(xsb + r * 512 + slot * 16) = h;
        }
    }
    __syncthreads();

    // compute
    int l = t & 63;
    int w = t >> 6;
    int lr   = l & 15;            // fragment row/col within 16-tile
    int acol = l >> 4;            // k-subchunk 0..3
    int arow = (w << 4) | lr;     // local row 0..63
    int axor = arow & 7;
    int bxor = lr & 7;

    const char* xsb = reinterpret_cast<const char*>(xs);
    const char* wtb = reinterpret_cast<const char*>(wt);

    f32x4 acc0 = {0.f, 0.f, 0.f, 0.f};
    f32x4 acc1 = {0.f, 0.f, 0.f, 0.f};
#pragma unroll
    for (int ks = 0; ks < 8; ++ks) {
        int ak = (ks << 2) | acol;
        half8 Af = *reinterpret_cast<const half8*>(xsb + arow * 512 + ((ak ^ axor) << 4));
        half8 B0 = *reinterpret_cast<const half8*>(wtb + lr * 512 + ((ak ^ bxor) << 4));
        half8 B1 = *reinterpret_cast<const half8*>(wtb + (lr + 16) * 512 + ((ak ^ bxor) << 4));
        acc0 = __builtin_amdgcn_mfma_f32_16x16x32_f16(Af, B0, acc0, 0, 0, 0);
        acc1 = __builtin_amdgcn_mfma_f32_16x16x32_f16(Af, B1, acc1, 0, 0, 0);
    }

    // store: D row = 4*(l>>4)+i, col = l&15
    int c0 = lr;
    int orow0 = row0 + (w << 4) + (acol << 2);
    float b0 = bhw[c0];
    float b1 = bhw[c0 + 16];
#pragma unroll
    for (int i = 0; i < 4; ++i) {
        int row = orow0 + i;
        if (row < n) {
            hw[(size_t)row * OUT + c0]      = acc0[i] + b0;
            hw[(size_t)row * OUT + 16 + c0] = acc1[i] + b1;
        }
    }
}

// ---------------------------------------------------------------------------
// Gather: half-wave per node, lane = feature; norm recomputed from dinv.
// ---------------------------------------------------------------------------
__global__ __launch_bounds__(256) void gather_nodes(
    const int* __restrict__ edata,
    const int* __restrict__ off,   // END pointers after permute
    const int* __restrict__ cnt,
    const float* __restrict__ dinv, const float* __restrict__ hw,
    const float* __restrict__ gcn_b, float* __restrict__ out, int n)
{
    int gid = blockIdx.x * 256 + threadIdx.x;
    int node = gid >> 5;
    int c    = gid & 31;
    if (node >= n) return;

    float di  = dinv[node];
    float acc = di * di * hw[(size_t)node * OUT + c];   // self loop
    int end = off[node];
    int num = cnt[node];
    int j = end - num;

    for (; j + 1 < end; j += 2) {
        int s0 = edata[j];
        int s1 = edata[j + 1];
        float n0 = dinv[s0] * di;
        float n1 = dinv[s1] * di;
        acc += n0 * hw[(size_t)s0 * OUT + c];
        acc += n1 * hw[(size_t)s1 * OUT + c];
    }
    if (j < end) {
        int s0 = edata[j];
        acc += dinv[s0] * di * hw[(size_t)s0 * OUT + c];
    }
    out[(size_t)node * OUT + c] = acc + gcn_b[c];
}

// ---------------------------------------------------------------------------
extern "C" void kernel_launch(void* const* d_in, const int* in_sizes, int n_in,
                              void* d_out, int out_size, void* d_ws, size_t ws_size,
                              hipStream_t stream)
{
    const float* x      = (const float*)d_in[0];
    const int*   eidx   = (const int*)d_in[1];
    const float* fc1_w  = (const float*)d_in[2];
    const float* fc1_b  = (const float*)d_in[3];
    const float* gcn_w  = (const float*)d_in[4];
    const float* gcn_b  = (const float*)d_in[5];
    float* out = (float*)d_out;

    int n = in_sizes[0] / IN_FEAT;
    int E = in_sizes[1] / 2;
    const int* src = eidx;
    const int* dst = eidx + E;

    int nb = (n + 1023) / 1024;

    auto align4 = [](size_t v) { return (v + 3) & ~(size_t)3; };
    float* ws = (float*)d_ws;
    size_t o = 0;
    _Float16* wsw = (_Float16*)(ws + o); o = align4(o + 4096);   // 32*256 f16
    float* bhw  = ws + o; o = align4(o + OUT);
    float* dinv = ws + o; o = align4(o + n);
    int*   cnt  = (int*)(ws + o); o = align4(o + n);
    int*   off  = (int*)(ws + o); o = align4(o + n);
    int*   bsum = (int*)(ws + o); o = align4(o + nb + 16);
    int*   edata = (int*)(ws + o); o = align4(o + (size_t)E);
    float* hw   = ws + o; o = align4(o + (size_t)n * OUT);
    (void)ws_size;

    dim3 blk(256);
    prep_W<<<dim3((IN_FEAT * OUT) / 256), blk, 0, stream>>>(fc1_w, fc1_b, gcn_w, wsw, bhw);
    zero_cnt<<<dim3((n + 255) / 256), blk, 0, stream>>>(cnt, n);
    count_deg<<<dim3((E + 255) / 256), blk, 0, stream>>>(dst, cnt, E);
    scan1<<<dim3(nb), blk, 0, stream>>>(cnt, bsum, n);
    scan2<<<dim3(1), dim3(64), 0, stream>>>(bsum, nb);
    scan3<<<dim3(nb), blk, 0, stream>>>(cnt, bsum, off, dinv, n);
    permute_edges<<<dim3((E + 255) / 256), blk, 0, stream>>>(src, dst, off, edata, E);
    gemm_mfma<<<dim3((n + 63) / 64), blk, 0, stream>>>(x, wsw, bhw, hw, n);
    long long total = (long long)n * OUT;
    gather_nodes<<<dim3((int)((total + 255) / 256)), blk, 0, stream>>>(
        edata, off, cnt, dinv, hw, gcn_b, out, n);
}

// Round 5
// 337.818 us; speedup vs baseline: 1.3822x; 1.3822x over previous
//
#include <hip/hip_runtime.h>
#include <hip/hip_fp16.h>

constexpr int IN_FEAT = 256;
constexpr int HID     = 64;
constexpr int OUT     = 32;

typedef _Float16 half8 __attribute__((ext_vector_type(8)));
typedef float    f32x4 __attribute__((ext_vector_type(4)));

// ---------------------------------------------------------------------------
// Fold the two linears into W = fc1_w^T @ gcn_w  [256,32], bhw = fc1_b @ gcn_w.
// Emit W as f16, TRANSPOSED [c][k] and XOR-swizzled for conflict-free b128
// LDS reads in the MFMA gemm:  f16 offset = c*256 + ((k>>3)^(c&7))*8 + (k&7).
// ---------------------------------------------------------------------------
__global__ __launch_bounds__(256) void prep_W(
    const float* __restrict__ fc1_w,   // [HID][IN_FEAT]
    const float* __restrict__ fc1_b,   // [HID]
    const float* __restrict__ gcn_w,   // [HID][OUT]
    _Float16* __restrict__ wsw,        // [32*256] f16, swizzled image
    float* __restrict__ bhw)           // [OUT]
{
    int idx = blockIdx.x * 256 + threadIdx.x;   // 0 .. 8191
    int k = idx >> 5;
    int c = idx & 31;
    float acc = 0.f;
#pragma unroll
    for (int h = 0; h < HID; ++h)
        acc += fc1_w[h * IN_FEAT + k] * gcn_w[h * OUT + c];
    wsw[c * 256 + (((k >> 3) ^ (c & 7)) << 3) + (k & 7)] = (_Float16)acc;

    if (idx < OUT) {
        float b = 0.f;
#pragma unroll
        for (int h = 0; h < HID; ++h)
            b += fc1_b[h] * gcn_w[h * OUT + idx];
        bhw[idx] = b;
    }
}

// ---------------------------------------------------------------------------
// Degree: zero, count in-edges (int atomics, L2-resident), dinv = rsqrt(deg+1).
// ---------------------------------------------------------------------------
__global__ __launch_bounds__(256) void zero_cnt(int* __restrict__ cnt, int n)
{
    int i = blockIdx.x * 256 + threadIdx.x;
    if (i < n) cnt[i] = 0;
}

__global__ __launch_bounds__(256) void count_deg(
    const int* __restrict__ dst, int* __restrict__ cnt, int E)
{
    int e = blockIdx.x * 256 + threadIdx.x;
    if (e < E) atomicAdd(&cnt[dst[e]], 1);
}

__global__ __launch_bounds__(256) void make_dinv(
    const int* __restrict__ cnt, float* __restrict__ dinv, int n)
{
    int i = blockIdx.x * 256 + threadIdx.x;
    if (i < n) dinv[i] = rsqrtf((float)(cnt[i] + 1));
}

// ---------------------------------------------------------------------------
// MFMA GEMM: hw = f16(x) @ f16(W) + bhw, stored as f16 [N][32].
// Epilogue also initializes the f16 output accumulator:
//   oacc[i][c] = f16( gcn_b[c] + dinv[i]^2 * hw[i][c] )        (self loop + bias)
// Block: 256 thr / 4 waves, 64 rows. LDS: xs [64][256] + wt [32][256] f16,
// XOR-swizzled per 16B slot (slot = chunk ^ (row&7)) = 48 KB -> 3 blk/CU.
// Fragment maps (CDNA contiguous-8):
//   A[r][k]: lane=r+16*(k/8), elem=k%8;  B[k][c]: lane=c+16*(k/8), elem=k%8;
//   D[r][c]: lane=c+16*(r/4), reg=r%4.      (verified: R4 passed, absmax 7.8e-3)
// ---------------------------------------------------------------------------
__global__ __launch_bounds__(256) void gemm_mfma(
    const float* __restrict__ x,        // [N][256] f32
    const _Float16* __restrict__ wsw,   // [32*256] f16 swizzled
    const float* __restrict__ bhw,      // [32]
    const float* __restrict__ dinv,     // [N]
    const float* __restrict__ gcn_b,    // [32]
    _Float16* __restrict__ hw2,         // [N][32] f16
    _Float16* __restrict__ oacc,        // [N][32] f16
    int n)
{
    __shared__ __align__(16) _Float16 xs[64 * 256];   // 32 KB
    __shared__ __align__(16) _Float16 wt[32 * 256];   // 16 KB

    int t = threadIdx.x;

    // stage W: straight 16 KB copy (already swizzled in global)
    {
        const float4* wg = reinterpret_cast<const float4*>(wsw);
        float4* wl = reinterpret_cast<float4*>(wt);
#pragma unroll
        for (int i = 0; i < 4; ++i)
            wl[t + 256 * i] = wg[t + 256 * i];
    }

    // stage x: 64 rows. half-wave h handles rows h, h+8, ..., lanes cover k.
    int row0 = blockIdx.x * 64;
    {
        int hwid = t >> 5;          // 0..7
        int lk   = t & 31;          // k-chunk (8 floats each)
        const float4* xg = reinterpret_cast<const float4*>(x);
        float4 A[8], B[8];
#pragma unroll
        for (int g = 0; g < 8; ++g) {
            int r = g * 8 + hwid;
            int row = row0 + r;
            A[g] = make_float4(0.f, 0.f, 0.f, 0.f);
            B[g] = make_float4(0.f, 0.f, 0.f, 0.f);
            if (row < n) {
                const float4* p = xg + (size_t)row * 64 + lk * 2;
                A[g] = p[0];
                B[g] = p[1];
            }
        }
        char* xsb = reinterpret_cast<char*>(xs);
#pragma unroll
        for (int g = 0; g < 8; ++g) {
            int r = g * 8 + hwid;
            half8 h;
            h[0] = (_Float16)A[g].x; h[1] = (_Float16)A[g].y;
            h[2] = (_Float16)A[g].z; h[3] = (_Float16)A[g].w;
            h[4] = (_Float16)B[g].x; h[5] = (_Float16)B[g].y;
            h[6] = (_Float16)B[g].z; h[7] = (_Float16)B[g].w;
            int slot = lk ^ (r & 7);
            *reinterpret_cast<half8*>(xsb + r * 512 + slot * 16) = h;
        }
    }
    __syncthreads();

    // compute
    int l = t & 63;
    int w = t >> 6;
    int lr   = l & 15;            // fragment row/col within 16-tile
    int acol = l >> 4;            // k-subchunk 0..3
    int arow = (w << 4) | lr;     // local row 0..63
    int axor = arow & 7;
    int bxor = lr & 7;

    const char* xsb = reinterpret_cast<const char*>(xs);
    const char* wtb = reinterpret_cast<const char*>(wt);

    f32x4 acc0 = {0.f, 0.f, 0.f, 0.f};
    f32x4 acc1 = {0.f, 0.f, 0.f, 0.f};
#pragma unroll
    for (int ks = 0; ks < 8; ++ks) {
        int ak = (ks << 2) | acol;
        half8 Af = *reinterpret_cast<const half8*>(xsb + arow * 512 + ((ak ^ axor) << 4));
        half8 B0 = *reinterpret_cast<const half8*>(wtb + lr * 512 + ((ak ^ bxor) << 4));
        half8 B1 = *reinterpret_cast<const half8*>(wtb + (lr + 16) * 512 + ((ak ^ bxor) << 4));
        acc0 = __builtin_amdgcn_mfma_f32_16x16x32_f16(Af, B0, acc0, 0, 0, 0);
        acc1 = __builtin_amdgcn_mfma_f32_16x16x32_f16(Af, B1, acc1, 0, 0, 0);
    }

    // store: D row = 4*(l>>4)+i, col = l&15
    int c0 = lr;
    int orow0 = row0 + (w << 4) + (acol << 2);
    float b0  = bhw[c0];
    float b1  = bhw[c0 + 16];
    float gb0 = gcn_b[c0];
    float gb1 = gcn_b[c0 + 16];
#pragma unroll
    for (int i = 0; i < 4; ++i) {
        int row = orow0 + i;
        if (row < n) {
            float h0 = acc0[i] + b0;
            float h1 = acc1[i] + b1;
            hw2[(size_t)row * OUT + c0]      = (_Float16)h0;
            hw2[(size_t)row * OUT + 16 + c0] = (_Float16)h1;
            float di = dinv[row];
            float d2 = di * di;
            oacc[(size_t)row * OUT + c0]      = (_Float16)(gb0 + d2 * h0);
            oacc[(size_t)row * OUT + 16 + c0] = (_Float16)(gb1 + d2 * h1);
        }
    }
}

// ---------------------------------------------------------------------------
// Edge scatter with packed-f16 atomics: 16 lanes per edge, lane = half2 pair.
//   oacc[d][2c:2c+2] += dinv[s]*dinv[d] * hw2[s][2c:2c+2]
// unsafeAtomicAdd -> global_atomic_pk_add_f16 (native, no CAS loop).
// ---------------------------------------------------------------------------
__global__ __launch_bounds__(256) void scatter_f16(
    const int* __restrict__ src, const int* __restrict__ dst,
    const float* __restrict__ dinv,
    const __half2* __restrict__ hw2,     // [N][16] half2
    __half2* __restrict__ oacc,          // [N][16] half2
    int E)
{
    int t = blockIdx.x * 256 + threadIdx.x;
    int e = t >> 4;
    int c = t & 15;
    if (e >= E) return;
    int s = src[e];
    int d = dst[e];
    float w = dinv[s] * dinv[d];
    __half2 hv = hw2[(size_t)s * 16 + c];
    __half2 val = __floats2half2_rn(w * __low2float(hv), w * __high2float(hv));
    unsafeAtomicAdd(&oacc[(size_t)d * 16 + c], val);
}

// ---------------------------------------------------------------------------
// Final convert f16 accumulator -> f32 output.
// ---------------------------------------------------------------------------
__global__ __launch_bounds__(256) void convert_out(
    const __half2* __restrict__ oacc, float2* __restrict__ out, int n16)
{
    int i = blockIdx.x * 256 + threadIdx.x;
    if (i >= n16) return;
    __half2 h = oacc[i];
    out[i] = make_float2(__low2float(h), __high2float(h));
}

// ---------------------------------------------------------------------------
extern "C" void kernel_launch(void* const* d_in, const int* in_sizes, int n_in,
                              void* d_out, int out_size, void* d_ws, size_t ws_size,
                              hipStream_t stream)
{
    const float* x      = (const float*)d_in[0];
    const int*   eidx   = (const int*)d_in[1];
    const float* fc1_w  = (const float*)d_in[2];
    const float* fc1_b  = (const float*)d_in[3];
    const float* gcn_w  = (const float*)d_in[4];
    const float* gcn_b  = (const float*)d_in[5];
    float* out = (float*)d_out;

    int n = in_sizes[0] / IN_FEAT;
    int E = in_sizes[1] / 2;
    const int* src = eidx;
    const int* dst = eidx + E;

    auto align4 = [](size_t v) { return (v + 3) & ~(size_t)3; };
    float* ws = (float*)d_ws;
    size_t o = 0;
    _Float16* wsw  = (_Float16*)(ws + o); o = align4(o + 4096);        // 32*256 f16
    float*    bhw  = ws + o;              o = align4(o + OUT);
    float*    dinv = ws + o;              o = align4(o + n);
    int*      cnt  = (int*)(ws + o);      o = align4(o + n);
    _Float16* hw2  = (_Float16*)(ws + o); o = align4(o + (size_t)n * OUT / 2);
    _Float16* oacc = (_Float16*)(ws + o); o = align4(o + (size_t)n * OUT / 2);
    (void)ws_size;

    dim3 blk(256);
    prep_W<<<dim3((IN_FEAT * OUT) / 256), blk, 0, stream>>>(fc1_w, fc1_b, gcn_w, wsw, bhw);
    zero_cnt<<<dim3((n + 255) / 256), blk, 0, stream>>>(cnt, n);
    count_deg<<<dim3((E + 255) / 256), blk, 0, stream>>>(dst, cnt, E);
    make_dinv<<<dim3((n + 255) / 256), blk, 0, stream>>>(cnt, dinv, n);
    gemm_mfma<<<dim3((n + 63) / 64), blk, 0, stream>>>(
        x, wsw, bhw, dinv, gcn_b, hw2, oacc, n);
    long long sthreads = (long long)E * 16;
    scatter_f16<<<dim3((int)((sthreads + 255) / 256)), blk, 0, stream>>>(
        src, dst, dinv, (const __half2*)hw2, (__half2*)oacc, E);
    int n16 = n * OUT / 2;
    convert_out<<<dim3((n16 + 255) / 256), blk, 0, stream>>>(
        (const __half2*)oacc, (float2*)out, n16);
}